// Round 1
// baseline (350.954 us; speedup 1.0000x reference)
//
#include <hip/hip_runtime.h>
#include <stdint.h>

// Shapes (fixed for this problem)
//   x      [4,2048,1024] f32
//   qkv_w  [3072,1024]   f32
//   out_w  [1024,1024]   f32
//   out_b  [1024]        f32
//   out    [4,2048,1024] f32
// Pipeline: cvt->bf16, GEMM qkv = x@qkv_w^T, flash attn, GEMM out = attn@out_w^T + b

typedef __bf16 bfx8 __attribute__((ext_vector_type(8)));
typedef float f32x4 __attribute__((ext_vector_type(4)));

__device__ __forceinline__ uint16_t f2b(float f) {
  uint32_t u = __float_as_uint(f);
  u += 0x7fff + ((u >> 16) & 1);   // RNE
  return (uint16_t)(u >> 16);
}

__device__ __forceinline__ void gld16(const void* g, void* l) {
  __builtin_amdgcn_global_load_lds((const __attribute__((address_space(1))) void*)g,
                                   (__attribute__((address_space(3))) void*)l,
                                   16, 0, 0);
}

// ---------------- f32 -> bf16 convert (8 elems/thread) ----------------
__global__ __launch_bounds__(256) void cvt_bf16(const float* __restrict__ in,
                                                uint16_t* __restrict__ out, int n8) {
  int i = blockIdx.x * 256 + threadIdx.x;
  if (i >= n8) return;
  float4 a = ((const float4*)in)[2 * i];
  float4 b = ((const float4*)in)[2 * i + 1];
  union { uint16_t u[8]; uint4 v; } pk;
  pk.u[0] = f2b(a.x); pk.u[1] = f2b(a.y); pk.u[2] = f2b(a.z); pk.u[3] = f2b(a.w);
  pk.u[4] = f2b(b.x); pk.u[5] = f2b(b.y); pk.u[6] = f2b(b.z); pk.u[7] = f2b(b.w);
  ((uint4*)out)[i] = pk.v;
}

// ---------------- GEMM: C[M,N] = A[M,K] * B[N,K]^T (+bias) ----------------
// 128x128 tile, BK=32, 256 threads (4 waves, 2x2 of 64x64), global_load_lds staging,
// double-buffered LDS, mfma_f32_16x16x32_bf16. m97-style structure.
template <int OUTF32>
__global__ __launch_bounds__(256) void gemm_bt(const uint16_t* __restrict__ A,
                                               const uint16_t* __restrict__ B,
                                               void* __restrict__ Cout,
                                               const float* __restrict__ bias,
                                               int M, int N, int K, int nbx, int nwg) {
  __shared__ alignas(16) uint16_t As[2][128 * 32];
  __shared__ alignas(16) uint16_t Bs[2][128 * 32];

  // bijective XCD swizzle (nwg % 8 == 0 for all our launches)
  int did = blockIdx.x;
  int wg = (did & 7) * (nwg >> 3) + (did >> 3);
  int bx = wg % nbx, by = wg / nbx;
  int m0 = by * 128, n0 = bx * 128;

  int tid = threadIdx.x;
  int lane = tid & 63, wid = tid >> 6;
  int wm = wid >> 1, wn = wid & 1;

  int rs = wid * 16 + (lane >> 2);  // staging row (it0); it1 = +64
  int cs = (lane & 3) * 8;          // staging col

  f32x4 acc[4][4] = {};

  auto stage = [&](int buf, int kt) {
    int k0 = kt * 32;
    gld16(&A[(size_t)(m0 + rs) * K + k0 + cs],      &As[buf][wid * 512]);
    gld16(&A[(size_t)(m0 + rs + 64) * K + k0 + cs], &As[buf][wid * 512 + 2048]);
    gld16(&B[(size_t)(n0 + rs) * K + k0 + cs],      &Bs[buf][wid * 512]);
    gld16(&B[(size_t)(n0 + rs + 64) * K + k0 + cs], &Bs[buf][wid * 512 + 2048]);
  };

  stage(0, 0);
  __syncthreads();

  int nk = K >> 5;
  int cur = 0;
  int ko = (lane >> 4) * 8;
  for (int kt = 0; kt < nk; ++kt) {
    if (kt + 1 < nk) stage(cur ^ 1, kt + 1);
    bfx8 a[4], b[4];
#pragma unroll
    for (int mi = 0; mi < 4; ++mi)
      a[mi] = *(const bfx8*)&As[cur][(wm * 64 + mi * 16 + (lane & 15)) * 32 + ko];
#pragma unroll
    for (int ni = 0; ni < 4; ++ni)
      b[ni] = *(const bfx8*)&Bs[cur][(wn * 64 + ni * 16 + (lane & 15)) * 32 + ko];
#pragma unroll
    for (int mi = 0; mi < 4; ++mi)
#pragma unroll
      for (int ni = 0; ni < 4; ++ni)
        acc[mi][ni] =
            __builtin_amdgcn_mfma_f32_16x16x32_bf16(a[mi], b[ni], acc[mi][ni], 0, 0, 0);
    __syncthreads();  // drains vmcnt (staged loads) + lgkmcnt; next iter flips buffers
    cur ^= 1;
  }

  // epilogue: C/D layout col=lane&15, row=(lane>>4)*4+r
#pragma unroll
  for (int mi = 0; mi < 4; ++mi) {
    int row = m0 + wm * 64 + mi * 16 + ((lane >> 4) << 2);
#pragma unroll
    for (int ni = 0; ni < 4; ++ni) {
      int col = n0 + wn * 64 + ni * 16 + (lane & 15);
#pragma unroll
      for (int r = 0; r < 4; ++r) {
        float v = acc[mi][ni][r];
        if (OUTF32)
          ((float*)Cout)[(size_t)(row + r) * N + col] = v + bias[col];
        else
          ((uint16_t*)Cout)[(size_t)(row + r) * N + col] = f2b(v);
      }
    }
  }
}

// ---------------- flash attention (causal) ----------------
// qkv: bf16 [B*T, 3072], e = s*1024 + h*64 + hd. attnb: bf16 [B*T, 1024] (col = h*64+hd).
// Block = (b,h, 64 q-rows); 4 waves x 16 q-rows. KV tile = 64.
// LDS XOR swizzle everywhere: elem(row,col) stored at row*64 + (col ^ ((row&7)<<3)).
__global__ __launch_bounds__(256) void flash_attn(const uint16_t* __restrict__ qkv,
                                                  uint16_t* __restrict__ attnb) {
  const int T = 2048, D3 = 3072;
  __shared__ alignas(16) uint16_t Ks[64 * 64];
  __shared__ alignas(16) uint16_t Vt[64 * 64];   // transposed: [hd][kv]
  __shared__ alignas(16) uint16_t Ps[4][16 * 64];

  int b = blockIdx.y >> 4, h = blockIdx.y & 15;
  int q0 = (int)(gridDim.x - 1 - blockIdx.x) * 64;  // longest blocks first
  int tid = threadIdx.x, lane = tid & 63, wid = tid >> 6;
  int qw = q0 + wid * 16;
  int ko = (lane >> 4) * 8;

  size_t base = (size_t)b * T * D3;

  // Q fragments in registers (A-operand: row=lane&15, k=(lane>>4)*8+j)
  bfx8 qf[2];
  {
    const uint16_t* qp = &qkv[base + (size_t)(qw + (lane & 15)) * D3 + h * 64 + ko];
    qf[0] = *(const bfx8*)qp;
    qf[1] = *(const bfx8*)(qp + 32);
  }

  float m_r[4] = {-1e30f, -1e30f, -1e30f, -1e30f};
  float l_r[4] = {0.f, 0.f, 0.f, 0.f};
  f32x4 acc_o[4] = {};

  int ntile = (q0 >> 6) + 1;
  // K staging coords (pre-swizzled global source so linear gld16 lands swizzled LDS)
  int krow = wid * 8 + (lane >> 3);
  int kc = ((lane & 7) << 3) ^ ((krow & 7) << 3);

  for (int kt = 0; kt < ntile; ++kt) {
    int kv0 = kt << 6;
    __syncthreads();  // previous tile fully consumed
    gld16(&qkv[base + (size_t)(kv0 + krow) * D3 + 1024 + h * 64 + kc], &Ks[wid * 512]);
    gld16(&qkv[base + (size_t)(kv0 + krow + 32) * D3 + 1024 + h * 64 + kc],
          &Ks[wid * 512 + 2048]);
    // V transposed staging: lane = kv row, wave covers 2 hd-blocks of 8
#pragma unroll
    for (int ii = 0; ii < 2; ++ii) {
      int c = (wid * 2 + ii) << 3;
      union { uint4 v; uint16_t u[8]; } raw;
      raw.v = *(const uint4*)&qkv[base + (size_t)(kv0 + lane) * D3 + 2048 + h * 64 + c];
#pragma unroll
      for (int j = 0; j < 8; ++j) {
        int hd = c + j;
        Vt[hd * 64 + (lane ^ ((hd & 7) << 3))] = raw.u[j];
      }
    }
    __syncthreads();

    // S = Q K^T  (B-operand: col=lane&15 -> kv, k=hd)
    f32x4 s[4] = {};
#pragma unroll
    for (int kk = 0; kk < 2; ++kk)
#pragma unroll
      for (int ni = 0; ni < 4; ++ni) {
        int row = ni * 16 + (lane & 15);
        bfx8 kf = *(const bfx8*)&Ks[row * 64 + ((kk * 32 + ko) ^ ((row & 7) << 3))];
        s[ni] = __builtin_amdgcn_mfma_f32_16x16x32_bf16(qf[kk], kf, s[ni], 0, 0, 0);
      }

    // scale + causal mask + online softmax (rows owned by 16-lane groups)
    float p[4][4];
    float mloc[4] = {-1e30f, -1e30f, -1e30f, -1e30f};
    int qrow0 = qw + ((lane >> 4) << 2);
    int col0 = kv0 + (lane & 15);
#pragma unroll
    for (int ni = 0; ni < 4; ++ni)
#pragma unroll
      for (int r = 0; r < 4; ++r) {
        float v = s[ni][r] * 0.125f;
        if (col0 + ni * 16 > qrow0 + r) v = -1e30f;
        p[ni][r] = v;
        mloc[r] = fmaxf(mloc[r], v);
      }
#pragma unroll
    for (int off = 1; off < 16; off <<= 1)
#pragma unroll
      for (int r = 0; r < 4; ++r) mloc[r] = fmaxf(mloc[r], __shfl_xor(mloc[r], off));
    float fac[4];
#pragma unroll
    for (int r = 0; r < 4; ++r) {
      float mn = fmaxf(m_r[r], mloc[r]);
      fac[r] = __expf(m_r[r] - mn);
      m_r[r] = mn;
    }
    float lloc[4] = {0.f, 0.f, 0.f, 0.f};
#pragma unroll
    for (int ni = 0; ni < 4; ++ni)
#pragma unroll
      for (int r = 0; r < 4; ++r) {
        float e = __expf(p[ni][r] - m_r[r]);
        p[ni][r] = e;
        lloc[r] += e;
      }
#pragma unroll
    for (int off = 1; off < 16; off <<= 1)
#pragma unroll
      for (int r = 0; r < 4; ++r) lloc[r] += __shfl_xor(lloc[r], off);
#pragma unroll
    for (int r = 0; r < 4; ++r) l_r[r] = l_r[r] * fac[r] + lloc[r];
#pragma unroll
    for (int f = 0; f < 4; ++f)
#pragma unroll
      for (int r = 0; r < 4; ++r) acc_o[f][r] *= fac[r];

    // P -> per-wave LDS (re-layout C/D -> A-operand), swizzled
    uint16_t* pw = &Ps[wid][0];
#pragma unroll
    for (int ni = 0; ni < 4; ++ni)
#pragma unroll
      for (int r = 0; r < 4; ++r) {
        int row = ((lane >> 4) << 2) + r;
        int col = ni * 16 + (lane & 15);
        pw[row * 64 + (col ^ ((row & 7) << 3))] = f2b(p[ni][r]);
      }

    // O += P V   (A: P rows=q; B: V[kv][hd] from Vt[hd][kv])
#pragma unroll
    for (int kk = 0; kk < 2; ++kk) {
      int prow = lane & 15;
      bfx8 pa = *(const bfx8*)&pw[prow * 64 + ((kk * 32 + ko) ^ ((prow & 7) << 3))];
#pragma unroll
      for (int f = 0; f < 4; ++f) {
        int hd = f * 16 + (lane & 15);
        bfx8 vf = *(const bfx8*)&Vt[hd * 64 + ((kk * 32 + ko) ^ ((hd & 7) << 3))];
        acc_o[f] = __builtin_amdgcn_mfma_f32_16x16x32_bf16(pa, vf, acc_o[f], 0, 0, 0);
      }
    }
  }

  // epilogue: O / l -> bf16
#pragma unroll
  for (int r = 0; r < 4; ++r) {
    int row = qw + ((lane >> 4) << 2) + r;
    float rl = 1.0f / l_r[r];
#pragma unroll
    for (int f = 0; f < 4; ++f)
      attnb[(size_t)(b * T + row) * 1024 + h * 64 + f * 16 + (lane & 15)] =
          f2b(acc_o[f][r] * rl);
  }
}

// ---------------- host ----------------
extern "C" void kernel_launch(void* const* d_in, const int* in_sizes, int n_in,
                              void* d_out, int out_size, void* d_ws, size_t ws_size,
                              hipStream_t stream) {
  const float* x = (const float*)d_in[0];
  const float* qkv_w = (const float*)d_in[1];
  const float* out_w = (const float*)d_in[2];
  const float* out_b = (const float*)d_in[3];
  float* out = (float*)d_out;

  char* ws = (char*)d_ws;
  // ws layout (bytes): xb 16MB | qkvb 48MB | attnb 16MB | wqkvb 6MB | wob 2MB  (= 88MB)
  uint16_t* xb    = (uint16_t*)(ws);
  uint16_t* qkvb  = (uint16_t*)(ws + 16777216);
  uint16_t* attnb = (uint16_t*)(ws + 67108864);
  uint16_t* wqkvb = (uint16_t*)(ws + 83886080);
  uint16_t* wob   = (uint16_t*)(ws + 90177536);

  cvt_bf16<<<4096, 256, 0, stream>>>(x, xb, 1048576);        // 8192*1024/8
  cvt_bf16<<<1536, 256, 0, stream>>>(qkv_w, wqkvb, 393216);  // 3072*1024/8
  cvt_bf16<<<512, 256, 0, stream>>>(out_w, wob, 131072);     // 1024*1024/8

  // qkv = x @ qkv_w^T : M=8192 N=3072 K=1024, grid 64*24=1536
  gemm_bt<0><<<1536, 256, 0, stream>>>(xb, wqkvb, (void*)qkvb, nullptr,
                                       8192, 3072, 1024, 24, 1536);
  // attention
  flash_attn<<<dim3(32, 64), 256, 0, stream>>>(qkvb, attnb);
  // out = attn @ out_w^T + b : M=8192 N=1024 K=1024, grid 64*8=512
  gemm_bt<1><<<512, 256, 0, stream>>>(attnb, wob, (void*)out, out_b,
                                      8192, 1024, 1024, 8, 512);
}

// Round 2
// 292.910 us; speedup vs baseline: 1.1982x; 1.1982x over previous
//
#include <hip/hip_runtime.h>
#include <stdint.h>

// Shapes (fixed): x [4,2048,1024] f32, qkv_w [3072,1024] f32, out_w [1024,1024] f32,
// out_b [1024] f32, out [4,2048,1024] f32.
// Pipeline: cvt->bf16, GEMM qkv = x@qkv_w^T, flash attn (S^T/O^T form), GEMM out.

typedef __bf16 bfx8 __attribute__((ext_vector_type(8)));
typedef float f32x4 __attribute__((ext_vector_type(4)));

__device__ __forceinline__ uint16_t f2b(float f) {
  uint32_t u = __float_as_uint(f);
  u += 0x7fff + ((u >> 16) & 1);   // RNE
  return (uint16_t)(u >> 16);
}

__device__ __forceinline__ uint32_t cvt_pk(float lo, float hi) {
  uint32_t r;
  asm("v_cvt_pk_bf16_f32 %0, %1, %2" : "=v"(r) : "v"(lo), "v"(hi));
  return r;
}

__device__ __forceinline__ void gld16(const void* g, void* l) {
  __builtin_amdgcn_global_load_lds((const __attribute__((address_space(1))) void*)g,
                                   (__attribute__((address_space(3))) void*)l,
                                   16, 0, 0);
}

// ---------------- f32 -> bf16 convert (8 elems/thread) ----------------
__global__ __launch_bounds__(256) void cvt_bf16(const float* __restrict__ in,
                                                uint16_t* __restrict__ out, int n8) {
  int i = blockIdx.x * 256 + threadIdx.x;
  if (i >= n8) return;
  float4 a = ((const float4*)in)[2 * i];
  float4 b = ((const float4*)in)[2 * i + 1];
  union { uint16_t u[8]; uint4 v; } pk;
  pk.u[0] = f2b(a.x); pk.u[1] = f2b(a.y); pk.u[2] = f2b(a.z); pk.u[3] = f2b(a.w);
  pk.u[4] = f2b(b.x); pk.u[5] = f2b(b.y); pk.u[6] = f2b(b.z); pk.u[7] = f2b(b.w);
  ((uint4*)out)[i] = pk.v;
}

// ---------------- GEMM: C[M,N] = A[M,K] * B[N,K]^T (+bias) ----------------
template <int OUTF32>
__global__ __launch_bounds__(256) void gemm_bt(const uint16_t* __restrict__ A,
                                               const uint16_t* __restrict__ B,
                                               void* __restrict__ Cout,
                                               const float* __restrict__ bias,
                                               int M, int N, int K, int nbx, int nwg) {
  __shared__ alignas(16) uint16_t As[2][128 * 32];
  __shared__ alignas(16) uint16_t Bs[2][128 * 32];

  int did = blockIdx.x;
  int wg = (did & 7) * (nwg >> 3) + (did >> 3);
  int bx = wg % nbx, by = wg / nbx;
  int m0 = by * 128, n0 = bx * 128;

  int tid = threadIdx.x;
  int lane = tid & 63, wid = tid >> 6;
  int wm = wid >> 1, wn = wid & 1;

  int rs = wid * 16 + (lane >> 2);
  int cs = (lane & 3) * 8;

  f32x4 acc[4][4] = {};

  auto stage = [&](int buf, int kt) {
    int k0 = kt * 32;
    gld16(&A[(size_t)(m0 + rs) * K + k0 + cs],      &As[buf][wid * 512]);
    gld16(&A[(size_t)(m0 + rs + 64) * K + k0 + cs], &As[buf][wid * 512 + 2048]);
    gld16(&B[(size_t)(n0 + rs) * K + k0 + cs],      &Bs[buf][wid * 512]);
    gld16(&B[(size_t)(n0 + rs + 64) * K + k0 + cs], &Bs[buf][wid * 512 + 2048]);
  };

  stage(0, 0);
  __syncthreads();

  int nk = K >> 5;
  int cur = 0;
  int ko = (lane >> 4) * 8;
  for (int kt = 0; kt < nk; ++kt) {
    if (kt + 1 < nk) stage(cur ^ 1, kt + 1);
    bfx8 a[4], b[4];
#pragma unroll
    for (int mi = 0; mi < 4; ++mi)
      a[mi] = *(const bfx8*)&As[cur][(wm * 64 + mi * 16 + (lane & 15)) * 32 + ko];
#pragma unroll
    for (int ni = 0; ni < 4; ++ni)
      b[ni] = *(const bfx8*)&Bs[cur][(wn * 64 + ni * 16 + (lane & 15)) * 32 + ko];
#pragma unroll
    for (int mi = 0; mi < 4; ++mi)
#pragma unroll
      for (int ni = 0; ni < 4; ++ni)
        acc[mi][ni] =
            __builtin_amdgcn_mfma_f32_16x16x32_bf16(a[mi], b[ni], acc[mi][ni], 0, 0, 0);
    __syncthreads();
    cur ^= 1;
  }

#pragma unroll
  for (int mi = 0; mi < 4; ++mi) {
    int row = m0 + wm * 64 + mi * 16 + ((lane >> 4) << 2);
#pragma unroll
    for (int ni = 0; ni < 4; ++ni) {
      int col = n0 + wn * 64 + ni * 16 + (lane & 15);
#pragma unroll
      for (int r = 0; r < 4; ++r) {
        float v = acc[mi][ni][r];
        if (OUTF32)
          ((float*)Cout)[(size_t)(row + r) * N + col] = v + bias[col];
        else
          ((uint16_t*)Cout)[(size_t)(row + r) * N + col] = f2b(v);
      }
    }
  }
}

// ---------------- flash attention (causal), S^T / O^T form ----------------
// Block = (b,h, 128 q-rows), 4 waves x 32 q (2 groups of 16). KV tile = 64.
// S^T = mfma(K, Q): lane owns q = qg + (lane&15); holds kv = ni*16 + 4G + r.
// O^T = mfma(V^T, P^T): acc col = q = lane&15 -> m/l/rescale all lane-local.
// LDS swizzle: elem(row,col) at row*64 + (col ^ ((row&7)<<3)).
__global__ __launch_bounds__(256) void flash_attn(const uint16_t* __restrict__ qkv,
                                                  uint16_t* __restrict__ attnb) {
  const int T = 2048, D3 = 3072;
  const float CSC = 0.125f * 1.44269504f;  // scale * log2(e)
  __shared__ alignas(16) uint16_t Ks[2][64 * 64];
  __shared__ alignas(16) uint16_t Vt[2][64 * 64];   // V^T: [hd][kv]
  __shared__ alignas(16) uint16_t Pt[4][32 * 64];   // per-wave P: [q_local][kv]

  int b = blockIdx.y >> 4, h = blockIdx.y & 15;
  int qb = (int)(gridDim.x - 1 - blockIdx.x);  // longest first
  int q0 = qb * 128;
  int tid = threadIdx.x, lane = tid & 63, wid = tid >> 6;
  int G = lane >> 4, l15 = lane & 15;
  int qw = q0 + wid * 32;
  int ko = G * 8;
  int sw = (l15 & 7) << 3;

  size_t base = (size_t)b * T * D3;
  int hoff = h * 64;

  // Q fragments (B-operand of S^T): col=q=l15, k=hd=kk*32+ko+j
  bfx8 qf[2][2];
#pragma unroll
  for (int g = 0; g < 2; ++g) {
    const uint16_t* qp = &qkv[base + (size_t)(qw + g * 16 + l15) * D3 + hoff + ko];
    qf[g][0] = *(const bfx8*)qp;
    qf[g][1] = *(const bfx8*)(qp + 32);
  }

  float mC[2] = {-1e30f, -1e30f};
  float l_r[2] = {0.f, 0.f};
  f32x4 accT[2][4] = {};   // [g][f]: col=q=l15, row=hd=f*16+4G+r

  int ntile = (q0 >> 6) + 2;

  const uint16_t* kbase = &qkv[base + 1024 + hoff];
  const uint16_t* vbase = &qkv[base + 2048 + hoff];

  // K staging (pre-swizzled global source, linear gld16 dest)
  int krow = wid * 8 + (lane >> 3);
  int kc = ((lane & 7) << 3) ^ ((krow & 7) << 3);
  // V staging: thread covers kv rows {vr, vr+1} at colblock vc
  int vr = (tid & 31) * 2;
  int vc = (tid >> 5) * 8;

  uint4 vreg0, vreg1;
  auto loadV = [&](int kv0) {
    vreg0 = *(const uint4*)&vbase[(size_t)(kv0 + vr) * D3 + vc];
    vreg1 = *(const uint4*)&vbase[(size_t)(kv0 + vr + 1) * D3 + vc];
  };
  auto stageK = [&](int buf, int kv0) {
    gld16(&kbase[(size_t)(kv0 + krow) * D3 + kc], &Ks[buf][wid * 512]);
    gld16(&kbase[(size_t)(kv0 + krow + 32) * D3 + kc], &Ks[buf][wid * 512 + 2048]);
  };
  auto writeV = [&](int buf) {
    union { uint4 v; uint16_t u[8]; } a, c;
    a.v = vreg0; c.v = vreg1;
#pragma unroll
    for (int j = 0; j < 8; ++j) {
      int hd = vc + j;
      uint32_t pk = (uint32_t)a.u[j] | ((uint32_t)c.u[j] << 16);
      *(uint32_t*)&Vt[buf][hd * 64 + (vr ^ ((hd & 7) << 3))] = pk;
    }
  };

  loadV(0);
  stageK(0, 0);
  writeV(0);
  __syncthreads();

  int cur = 0;
  for (int kt = 0; kt < ntile; ++kt) {
    int kv0 = kt << 6;
    bool pre = (kt + 1 < ntile);
    if (pre) { loadV((kt + 1) << 6); stageK(cur ^ 1, (kt + 1) << 6); }

#pragma unroll
    for (int g = 0; g < 2; ++g) {
      int qg = qw + g * 16;
      if (kv0 <= qg + 15) {   // wave-uniform: this tile intersects this row-group
        // S^T = K * Q^T
        f32x4 st[4] = {};
        __builtin_amdgcn_s_setprio(1);
#pragma unroll
        for (int ni = 0; ni < 4; ++ni) {
          int row = ni * 16 + l15;
          bfx8 kf0 = *(const bfx8*)&Ks[cur][row * 64 + ((0 + ko) ^ sw)];
          bfx8 kf1 = *(const bfx8*)&Ks[cur][row * 64 + ((32 + ko) ^ sw)];
          st[ni] = __builtin_amdgcn_mfma_f32_16x16x32_bf16(kf0, qf[g][0], st[ni], 0, 0, 0);
          st[ni] = __builtin_amdgcn_mfma_f32_16x16x32_bf16(kf1, qf[g][1], st[ni], 0, 0, 0);
        }
        __builtin_amdgcn_s_setprio(0);

        int q = qg + l15;
        float p[16];
        float mloc = -1e30f;
        if (kv0 + 63 > qg) {  // diagonal tile: apply causal mask
#pragma unroll
          for (int ni = 0; ni < 4; ++ni)
#pragma unroll
            for (int r = 0; r < 4; ++r) {
              int kv = kv0 + ni * 16 + 4 * G + r;
              float v = (kv > q) ? -1e30f : st[ni][r];
              p[ni * 4 + r] = v;
              mloc = fmaxf(mloc, v);
            }
        } else {
#pragma unroll
          for (int ni = 0; ni < 4; ++ni)
#pragma unroll
            for (int r = 0; r < 4; ++r) {
              float v = st[ni][r];
              p[ni * 4 + r] = v;
              mloc = fmaxf(mloc, v);
            }
        }
        mloc = fmaxf(mloc, __shfl_xor(mloc, 16));
        mloc = fmaxf(mloc, __shfl_xor(mloc, 32));
        float mCn = fmaxf(mC[g], mloc * CSC);
        float fac = __builtin_amdgcn_exp2f(mC[g] - mCn);
        mC[g] = mCn;
        float lsum = 0.f;
#pragma unroll
        for (int i = 0; i < 16; ++i) {
          float e = __builtin_amdgcn_exp2f(fmaf(p[i], CSC, -mCn));
          p[i] = e;
          lsum += e;
        }
        lsum += __shfl_xor(lsum, 16);
        lsum += __shfl_xor(lsum, 32);
        l_r[g] = l_r[g] * fac + lsum;
#pragma unroll
        for (int f = 0; f < 4; ++f) accT[g][f] *= fac;

        // P -> LDS (packed bf16 pairs, kv-contiguous)
        int prow = g * 16 + l15;
        uint16_t* pw = &Pt[wid][prow * 64];
#pragma unroll
        for (int ni = 0; ni < 4; ++ni) {
          int c0 = ni * 16 + 4 * G;
          *(uint32_t*)&pw[(c0) ^ sw] = cvt_pk(p[ni * 4 + 0], p[ni * 4 + 1]);
          *(uint32_t*)&pw[(c0 + 2) ^ sw] = cvt_pk(p[ni * 4 + 2], p[ni * 4 + 3]);
        }

        // O^T += V^T * P^T
        bfx8 pa0 = *(const bfx8*)&pw[(0 + 8 * G) ^ sw];
        bfx8 pa1 = *(const bfx8*)&pw[(32 + 8 * G) ^ sw];
        __builtin_amdgcn_s_setprio(1);
#pragma unroll
        for (int f = 0; f < 4; ++f) {
          int hd = f * 16 + l15;
          int hsw = (hd & 7) << 3;
          bfx8 v0 = *(const bfx8*)&Vt[cur][hd * 64 + ((0 + ko) ^ hsw)];
          bfx8 v1 = *(const bfx8*)&Vt[cur][hd * 64 + ((32 + ko) ^ hsw)];
          accT[g][f] = __builtin_amdgcn_mfma_f32_16x16x32_bf16(v0, pa0, accT[g][f], 0, 0, 0);
          accT[g][f] = __builtin_amdgcn_mfma_f32_16x16x32_bf16(v1, pa1, accT[g][f], 0, 0, 0);
        }
        __builtin_amdgcn_s_setprio(0);
      }
    }

    if (pre) writeV(cur ^ 1);
    __syncthreads();
    cur ^= 1;
  }

  // epilogue: normalize, transpose via Pt, coalesced bf16 store
#pragma unroll
  for (int g = 0; g < 2; ++g) {
    float rl = 1.0f / l_r[g];
    int prow = g * 16 + l15;
#pragma unroll
    for (int f = 0; f < 4; ++f) {
      int c0 = f * 16 + 4 * G;
      *(uint32_t*)&Pt[wid][prow * 64 + ((c0) ^ sw)] =
          cvt_pk(accT[g][f][0] * rl, accT[g][f][1] * rl);
      *(uint32_t*)&Pt[wid][prow * 64 + ((c0 + 2) ^ sw)] =
          cvt_pk(accT[g][f][2] * rl, accT[g][f][3] * rl);
    }
  }
  int row = lane >> 1;
  int cb = (lane & 1) * 32;
  int q = q0 + wid * 32 + row;
  int rsw = (row & 7) << 3;
  uint16_t* dst = &attnb[(size_t)(b * T + q) * 1024 + hoff + cb];
#pragma unroll
  for (int cc = 0; cc < 4; ++cc) {
    uint4 val = *(const uint4*)&Pt[wid][row * 64 + ((cb + cc * 8) ^ rsw)];
    *(uint4*)&dst[cc * 8] = val;
  }
}

// ---------------- host ----------------
extern "C" void kernel_launch(void* const* d_in, const int* in_sizes, int n_in,
                              void* d_out, int out_size, void* d_ws, size_t ws_size,
                              hipStream_t stream) {
  const float* x = (const float*)d_in[0];
  const float* qkv_w = (const float*)d_in[1];
  const float* out_w = (const float*)d_in[2];
  const float* out_b = (const float*)d_in[3];
  float* out = (float*)d_out;

  char* ws = (char*)d_ws;
  uint16_t* xb    = (uint16_t*)(ws);
  uint16_t* qkvb  = (uint16_t*)(ws + 16777216);
  uint16_t* attnb = (uint16_t*)(ws + 67108864);
  uint16_t* wqkvb = (uint16_t*)(ws + 83886080);
  uint16_t* wob   = (uint16_t*)(ws + 90177536);

  cvt_bf16<<<4096, 256, 0, stream>>>(x, xb, 1048576);
  cvt_bf16<<<1536, 256, 0, stream>>>(qkv_w, wqkvb, 393216);
  cvt_bf16<<<512, 256, 0, stream>>>(out_w, wob, 131072);

  gemm_bt<0><<<1536, 256, 0, stream>>>(xb, wqkvb, (void*)qkvb, nullptr,
                                       8192, 3072, 1024, 24, 1536);
  flash_attn<<<dim3(16, 64), 256, 0, stream>>>(qkvb, attnb);
  gemm_bt<1><<<512, 256, 0, stream>>>(attnb, wob, (void*)out, out_b,
                                      8192, 1024, 1024, 8, 512);
}

// Round 3
// 221.337 us; speedup vs baseline: 1.5856x; 1.3234x over previous
//
#include <hip/hip_runtime.h>
#include <stdint.h>

// Shapes (fixed): x [4,2048,1024] f32, qkv_w [3072,1024] f32, out_w [1024,1024] f32,
// out_b [1024] f32, out [4,2048,1024] f32.
// Pipeline: cvt->bf16, GEMM qkv = x@qkv_w^T, flash attn (32x32 S^T/O^T, in-reg softmax),
// GEMM out = attn@out_w^T + b.

typedef __bf16 bfx8 __attribute__((ext_vector_type(8)));
typedef float f32x4 __attribute__((ext_vector_type(4)));
typedef float f32x16 __attribute__((ext_vector_type(16)));

__device__ __forceinline__ uint16_t f2b(float f) {
  uint32_t u = __float_as_uint(f);
  u += 0x7fff + ((u >> 16) & 1);   // RNE
  return (uint16_t)(u >> 16);
}

__device__ __forceinline__ uint32_t cvt_pk(float lo, float hi) {
  uint32_t r;
  asm("v_cvt_pk_bf16_f32 %0, %1, %2" : "=v"(r) : "v"(lo), "v"(hi));
  return r;
}

__device__ __forceinline__ void gld16(const void* g, void* l) {
  __builtin_amdgcn_global_load_lds((const __attribute__((address_space(1))) void*)g,
                                   (__attribute__((address_space(3))) void*)l,
                                   16, 0, 0);
}

// ---------------- f32 -> bf16 convert (8 elems/thread) ----------------
__global__ __launch_bounds__(256) void cvt_bf16(const float* __restrict__ in,
                                                uint16_t* __restrict__ out, int n8) {
  int i = blockIdx.x * 256 + threadIdx.x;
  if (i >= n8) return;
  float4 a = ((const float4*)in)[2 * i];
  float4 b = ((const float4*)in)[2 * i + 1];
  union { uint16_t u[8]; uint4 v; } pk;
  pk.u[0] = f2b(a.x); pk.u[1] = f2b(a.y); pk.u[2] = f2b(a.z); pk.u[3] = f2b(a.w);
  pk.u[4] = f2b(b.x); pk.u[5] = f2b(b.y); pk.u[6] = f2b(b.z); pk.u[7] = f2b(b.w);
  ((uint4*)out)[i] = pk.v;
}

// ---------------- GEMM: C[M,N] = A[M,K] * B[N,K]^T (+bias) ----------------
template <int OUTF32>
__global__ __launch_bounds__(256) void gemm_bt(const uint16_t* __restrict__ A,
                                               const uint16_t* __restrict__ B,
                                               void* __restrict__ Cout,
                                               const float* __restrict__ bias,
                                               int M, int N, int K, int nbx, int nwg) {
  __shared__ alignas(16) uint16_t As[2][128 * 32];
  __shared__ alignas(16) uint16_t Bs[2][128 * 32];

  int did = blockIdx.x;
  int wg = (did & 7) * (nwg >> 3) + (did >> 3);
  int bx = wg % nbx, by = wg / nbx;
  int m0 = by * 128, n0 = bx * 128;

  int tid = threadIdx.x;
  int lane = tid & 63, wid = tid >> 6;
  int wm = wid >> 1, wn = wid & 1;

  int rs = wid * 16 + (lane >> 2);
  int cs = (lane & 3) * 8;

  f32x4 acc[4][4] = {};

  auto stage = [&](int buf, int kt) {
    int k0 = kt * 32;
    gld16(&A[(size_t)(m0 + rs) * K + k0 + cs],      &As[buf][wid * 512]);
    gld16(&A[(size_t)(m0 + rs + 64) * K + k0 + cs], &As[buf][wid * 512 + 2048]);
    gld16(&B[(size_t)(n0 + rs) * K + k0 + cs],      &Bs[buf][wid * 512]);
    gld16(&B[(size_t)(n0 + rs + 64) * K + k0 + cs], &Bs[buf][wid * 512 + 2048]);
  };

  stage(0, 0);
  __syncthreads();

  int nk = K >> 5;
  int cur = 0;
  int ko = (lane >> 4) * 8;
  for (int kt = 0; kt < nk; ++kt) {
    if (kt + 1 < nk) stage(cur ^ 1, kt + 1);
    bfx8 a[4], b[4];
#pragma unroll
    for (int mi = 0; mi < 4; ++mi)
      a[mi] = *(const bfx8*)&As[cur][(wm * 64 + mi * 16 + (lane & 15)) * 32 + ko];
#pragma unroll
    for (int ni = 0; ni < 4; ++ni)
      b[ni] = *(const bfx8*)&Bs[cur][(wn * 64 + ni * 16 + (lane & 15)) * 32 + ko];
#pragma unroll
    for (int mi = 0; mi < 4; ++mi)
#pragma unroll
      for (int ni = 0; ni < 4; ++ni)
        acc[mi][ni] =
            __builtin_amdgcn_mfma_f32_16x16x32_bf16(a[mi], b[ni], acc[mi][ni], 0, 0, 0);
    __syncthreads();
    cur ^= 1;
  }

#pragma unroll
  for (int mi = 0; mi < 4; ++mi) {
    int row = m0 + wm * 64 + mi * 16 + ((lane >> 4) << 2);
#pragma unroll
    for (int ni = 0; ni < 4; ++ni) {
      int col = n0 + wn * 64 + ni * 16 + (lane & 15);
#pragma unroll
      for (int r = 0; r < 4; ++r) {
        float v = acc[mi][ni][r];
        if (OUTF32)
          ((float*)Cout)[(size_t)(row + r) * N + col] = v + bias[col];
        else
          ((uint16_t*)Cout)[(size_t)(row + r) * N + col] = f2b(v);
      }
    }
  }
}

// ---------------- flash attention (causal), 32x32 S^T / O^T, in-reg softmax ----------
// 1024 blocks: bh = d&63, qb via Latin square on d>>6 (CU-coset load balance).
// 4 waves x 32 q rows. KV tile = 64 (2x 32-row sub-tiles), double-buffered K,V in LDS.
// S^T = mfma32x32x16(K, Q): lane q = qw + (lane&31); holds kv rows (r&3)+8*(r>>2)+4*hi.
// P->bf16 PV B-frag built in registers via cvt_pk + permlane32_swap (no LDS roundtrip).
// O^T = mfma32x32x16(V^T, P^T): acc col = q -> m/l/rescale lane-local.
// LDS swizzle: elem(row,col) at row*64 + (col ^ ((row&7)<<3)).
__global__ __launch_bounds__(256, 4) void flash_attn(const uint16_t* __restrict__ qkv,
                                                     uint16_t* __restrict__ attnb) {
  const int T = 2048, D3 = 3072;
  const float CSC = 0.125f * 1.44269504f;  // scale * log2(e)
  __shared__ alignas(16) uint16_t Ks[2][64 * 64];
  __shared__ alignas(16) uint16_t Vt[2][64 * 64];   // V^T: [hd][kv]

  int d = blockIdx.x;
  int bh = d & 63;
  int e = d >> 6;
  int hh = e >> 2, aa = e & 3;
  int qb = 4 * hh + ((aa + hh) & 3);   // Latin square: stride-256 cosets sum-balanced
  int b = bh >> 4, h = bh & 15;
  int q0 = qb * 128;

  int tid = threadIdx.x, lane = tid & 63, wid = tid >> 6;
  int l31 = lane & 31, hi = lane >> 5;
  int qw = q0 + wid * 32;
  int swz = (lane & 7) << 3;

  size_t base = (size_t)b * T * D3;
  int hoff = h * 64;
  const uint16_t* kbase = &qkv[base + 1024 + hoff];
  const uint16_t* vbase = &qkv[base + 2048 + hoff];

  // Q frags (B-operand): col=q=l31, k = hd = 16*h4 + 8*hi + j
  bfx8 qf[4];
  {
    const uint16_t* qp = &qkv[base + (size_t)(qw + l31) * D3 + hoff + 8 * hi];
#pragma unroll
    for (int h4 = 0; h4 < 4; ++h4) qf[h4] = *(const bfx8*)(qp + 16 * h4);
  }

  float mC = -1e30f, l_r = 0.f;
  f32x16 acc0 = {}, acc1 = {};

  int ntile = 2 * qb + 2;

  // K staging: wave stages 16 rows via 2 gld16 (pre-swizzled global source)
  int krow = wid * 16 + (lane >> 3);
  int kc = ((lane & 7) << 3) ^ ((krow & 7) << 3);
  // V staging: thread covers kv rows {vr, vr+1} at hd colblock vc
  int vr = (tid & 31) * 2;
  int vc = (tid >> 5) * 8;
  uint4 vreg0, vreg1;

  auto loadV = [&](int kv0) {
    vreg0 = *(const uint4*)&vbase[(size_t)(kv0 + vr) * D3 + vc];
    vreg1 = *(const uint4*)&vbase[(size_t)(kv0 + vr + 1) * D3 + vc];
  };
  auto stageK = [&](int buf, int kv0) {
    gld16(&kbase[(size_t)(kv0 + krow) * D3 + kc], &Ks[buf][wid * 1024]);
    gld16(&kbase[(size_t)(kv0 + krow + 8) * D3 + kc], &Ks[buf][wid * 1024 + 512]);
  };
  auto writeV = [&](int buf) {
    union { uint4 v; uint16_t u[8]; } a, c;
    a.v = vreg0; c.v = vreg1;
#pragma unroll
    for (int j = 0; j < 8; ++j) {
      int hd = vc + j;
      uint32_t pk = (uint32_t)a.u[j] | ((uint32_t)c.u[j] << 16);
      *(uint32_t*)&Vt[buf][hd * 64 + (vr ^ ((hd & 7) << 3))] = pk;
    }
  };

  loadV(0);
  stageK(0, 0);
  writeV(0);
  __syncthreads();

  int cur = 0;
  for (int kt = 0; kt < ntile; ++kt) {
    int kv0 = kt << 6;
    bool pre = (kt + 1 < ntile);
    if (pre) { loadV((kt + 1) << 6); stageK(cur ^ 1, (kt + 1) << 6); }

    if (kv0 <= qw) {   // wave-uniform causal skip
      // ---- S^T = K * Q^T ----
      f32x16 st[2] = {};
      __builtin_amdgcn_s_setprio(1);
#pragma unroll
      for (int h4 = 0; h4 < 4; ++h4) {
#pragma unroll
        for (int t = 0; t < 2; ++t) {
          bfx8 kf = *(const bfx8*)&Ks[cur][(32 * t + l31) * 64 + ((16 * h4 + 8 * hi) ^ swz)];
          st[t] = __builtin_amdgcn_mfma_f32_32x32x16_bf16(kf, qf[h4], st[t], 0, 0, 0);
        }
      }
      __builtin_amdgcn_s_setprio(0);

      // ---- softmax (lane-local rows; st becomes P in place) ----
      int q = qw + l31;
      float mloc = -1e30f;
#pragma unroll
      for (int t = 0; t < 2; ++t) {
        int kvt = kv0 + 32 * t;
        bool nm = (kvt + 31 > qw);   // wave-uniform: diagonal-or-beyond sub-tile
#pragma unroll
        for (int r = 0; r < 16; ++r) {
          float v = st[t][r];
          if (nm) {
            int kv = kvt + (r & 3) + 8 * (r >> 2) + 4 * hi;
            if (kv > q) v = -1e30f;
          }
          st[t][r] = v;
          mloc = fmaxf(mloc, v);
        }
      }
      float mS = mloc * CSC;
      mS = fmaxf(mS, __shfl_xor(mS, 32));
      if (!__all(mS - mC <= 8.0f)) {   // defer-max (T13)
        float mCn = fmaxf(mC, mS);
        float fac = __builtin_amdgcn_exp2f(mC - mCn);
        mC = mCn;
        l_r *= fac;
        acc0 *= fac;
        acc1 *= fac;
      }
      float lsum = 0.f;
#pragma unroll
      for (int t = 0; t < 2; ++t)
#pragma unroll
        for (int r = 0; r < 16; ++r) {
          float pe = __builtin_amdgcn_exp2f(fmaf(st[t][r], CSC, -mC));
          st[t][r] = pe;
          lsum += pe;
        }
      lsum += __shfl_xor(lsum, 32);
      l_r += lsum;

      // ---- O^T += V^T * P^T (P-frag in registers via cvt_pk + permlane32_swap) ----
      int smax = (qw + 31 - kv0) >> 4;
      __builtin_amdgcn_s_setprio(1);
#pragma unroll
      for (int s = 0; s < 4; ++s) {
        if (s <= smax) {
          int t = s >> 1, pb = 8 * (s & 1);
          uint32_t W0 = cvt_pk(st[t][pb + 0], st[t][pb + 1]);
          uint32_t W1 = cvt_pk(st[t][pb + 2], st[t][pb + 3]);
          uint32_t W2 = cvt_pk(st[t][pb + 4], st[t][pb + 5]);
          uint32_t W3 = cvt_pk(st[t][pb + 6], st[t][pb + 7]);
          auto rA = __builtin_amdgcn_permlane32_swap(W0, W2, false, false);
          auto rB = __builtin_amdgcn_permlane32_swap(W1, W3, false, false);
          union { uint32_t u[4]; bfx8 v; } pf;
          pf.u[0] = rA[0]; pf.u[1] = rB[0]; pf.u[2] = rA[1]; pf.u[3] = rB[1];
          bfx8 v0 = *(const bfx8*)&Vt[cur][l31 * 64 + ((16 * s + 8 * hi) ^ swz)];
          acc0 = __builtin_amdgcn_mfma_f32_32x32x16_bf16(v0, pf.v, acc0, 0, 0, 0);
          bfx8 v1 = *(const bfx8*)&Vt[cur][(32 + l31) * 64 + ((16 * s + 8 * hi) ^ swz)];
          acc1 = __builtin_amdgcn_mfma_f32_32x32x16_bf16(v1, pf.v, acc1, 0, 0, 0);
        }
      }
      __builtin_amdgcn_s_setprio(0);
    }

    if (pre) writeV(cur ^ 1);
    __syncthreads();
    cur ^= 1;
  }

  // ---- epilogue: normalize, transpose via LDS (overlay on Ks), coalesced store ----
  __syncthreads();
  uint16_t* ow = ((uint16_t*)Ks) + wid * 2048;  // per-warp [32 q][64 hd]
  float rl = 1.0f / l_r;
#pragma unroll
  for (int f = 0; f < 2; ++f) {
#pragma unroll
    for (int r = 0; r < 16; r += 2) {
      int hd = 32 * f + (r & 3) + 8 * (r >> 2) + 4 * hi;
      float v0 = (f ? acc1[r] : acc0[r]) * rl;
      float v1 = (f ? acc1[r + 1] : acc0[r + 1]) * rl;
      *(uint32_t*)&ow[l31 * 64 + (hd ^ ((l31 & 7) << 3))] = cvt_pk(v0, v1);
    }
  }
  __syncthreads();
  int row = lane >> 1, cb = (lane & 1) * 32;
  int q = q0 + wid * 32 + row;
  int rs = (row & 7) << 3;
  uint16_t* dst = &attnb[(size_t)(b * T + q) * 1024 + hoff + cb];
#pragma unroll
  for (int cc = 0; cc < 4; ++cc)
    *(uint4*)&dst[cc * 8] = *(const uint4*)&ow[row * 64 + ((cb + cc * 8) ^ rs)];
}

// ---------------- host ----------------
extern "C" void kernel_launch(void* const* d_in, const int* in_sizes, int n_in,
                              void* d_out, int out_size, void* d_ws, size_t ws_size,
                              hipStream_t stream) {
  const float* x = (const float*)d_in[0];
  const float* qkv_w = (const float*)d_in[1];
  const float* out_w = (const float*)d_in[2];
  const float* out_b = (const float*)d_in[3];
  float* out = (float*)d_out;

  char* ws = (char*)d_ws;
  uint16_t* xb    = (uint16_t*)(ws);
  uint16_t* qkvb  = (uint16_t*)(ws + 16777216);
  uint16_t* attnb = (uint16_t*)(ws + 67108864);
  uint16_t* wqkvb = (uint16_t*)(ws + 83886080);
  uint16_t* wob   = (uint16_t*)(ws + 90177536);

  cvt_bf16<<<4096, 256, 0, stream>>>(x, xb, 1048576);
  cvt_bf16<<<1536, 256, 0, stream>>>(qkv_w, wqkvb, 393216);
  cvt_bf16<<<512, 256, 0, stream>>>(out_w, wob, 131072);

  gemm_bt<0><<<1536, 256, 0, stream>>>(xb, wqkvb, (void*)qkvb, nullptr,
                                       8192, 3072, 1024, 24, 1536);
  flash_attn<<<1024, 256, 0, stream>>>(qkvb, attnb);
  gemm_bt<1><<<512, 256, 0, stream>>>(attnb, wob, (void*)out, out_b,
                                      8192, 1024, 1024, 8, 512);
}

// Round 4
// 197.323 us; speedup vs baseline: 1.7786x; 1.1217x over previous
//
#include <hip/hip_runtime.h>
#include <stdint.h>

// Shapes (fixed): x [4,2048,1024] f32, qkv_w [3072,1024] f32, out_w [1024,1024] f32,
// out_b [1024] f32, out [4,2048,1024] f32.
// Pipeline: cvt->bf16, GEMM qkv = x@qkv_w^T, flash attn (32x32 S^T/O^T, in-reg softmax,
// T15 cross-tile PV pipeline), GEMM out = attn@out_w^T + b.

typedef __bf16 bfx8 __attribute__((ext_vector_type(8)));
typedef float f32x4 __attribute__((ext_vector_type(4)));
typedef float f32x16 __attribute__((ext_vector_type(16)));

__device__ __forceinline__ uint16_t f2b(float f) {
  uint32_t u = __float_as_uint(f);
  u += 0x7fff + ((u >> 16) & 1);   // RNE
  return (uint16_t)(u >> 16);
}

__device__ __forceinline__ uint32_t cvt_pk(float lo, float hi) {
  uint32_t r;
  asm("v_cvt_pk_bf16_f32 %0, %1, %2" : "=v"(r) : "v"(lo), "v"(hi));
  return r;
}

__device__ __forceinline__ void gld16(const void* g, void* l) {
  __builtin_amdgcn_global_load_lds((const __attribute__((address_space(1))) void*)g,
                                   (__attribute__((address_space(3))) void*)l,
                                   16, 0, 0);
}

// ---------------- f32 -> bf16 convert (8 elems/thread) ----------------
__global__ __launch_bounds__(256) void cvt_bf16(const float* __restrict__ in,
                                                uint16_t* __restrict__ out, int n8) {
  int i = blockIdx.x * 256 + threadIdx.x;
  if (i >= n8) return;
  float4 a = ((const float4*)in)[2 * i];
  float4 b = ((const float4*)in)[2 * i + 1];
  union { uint16_t u[8]; uint4 v; } pk;
  pk.u[0] = f2b(a.x); pk.u[1] = f2b(a.y); pk.u[2] = f2b(a.z); pk.u[3] = f2b(a.w);
  pk.u[4] = f2b(b.x); pk.u[5] = f2b(b.y); pk.u[6] = f2b(b.z); pk.u[7] = f2b(b.w);
  ((uint4*)out)[i] = pk.v;
}

// ---------------- GEMM: C[M,N] = A[M,K] * B[N,K]^T (+bias) ----------------
template <int OUTF32>
__global__ __launch_bounds__(256) void gemm_bt(const uint16_t* __restrict__ A,
                                               const uint16_t* __restrict__ B,
                                               void* __restrict__ Cout,
                                               const float* __restrict__ bias,
                                               int M, int N, int K, int nbx, int nwg) {
  __shared__ alignas(16) uint16_t As[2][128 * 32];
  __shared__ alignas(16) uint16_t Bs[2][128 * 32];

  int did = blockIdx.x;
  int wg = (did & 7) * (nwg >> 3) + (did >> 3);
  int bx = wg % nbx, by = wg / nbx;
  int m0 = by * 128, n0 = bx * 128;

  int tid = threadIdx.x;
  int lane = tid & 63, wid = tid >> 6;
  int wm = wid >> 1, wn = wid & 1;

  int rs = wid * 16 + (lane >> 2);
  int cs = (lane & 3) * 8;

  f32x4 acc[4][4] = {};

  auto stage = [&](int buf, int kt) {
    int k0 = kt * 32;
    gld16(&A[(size_t)(m0 + rs) * K + k0 + cs],      &As[buf][wid * 512]);
    gld16(&A[(size_t)(m0 + rs + 64) * K + k0 + cs], &As[buf][wid * 512 + 2048]);
    gld16(&B[(size_t)(n0 + rs) * K + k0 + cs],      &Bs[buf][wid * 512]);
    gld16(&B[(size_t)(n0 + rs + 64) * K + k0 + cs], &Bs[buf][wid * 512 + 2048]);
  };

  stage(0, 0);
  __syncthreads();

  int nk = K >> 5;
  int cur = 0;
  int ko = (lane >> 4) * 8;
  for (int kt = 0; kt < nk; ++kt) {
    if (kt + 1 < nk) stage(cur ^ 1, kt + 1);
    bfx8 a[4], b[4];
#pragma unroll
    for (int mi = 0; mi < 4; ++mi)
      a[mi] = *(const bfx8*)&As[cur][(wm * 64 + mi * 16 + (lane & 15)) * 32 + ko];
#pragma unroll
    for (int ni = 0; ni < 4; ++ni)
      b[ni] = *(const bfx8*)&Bs[cur][(wn * 64 + ni * 16 + (lane & 15)) * 32 + ko];
#pragma unroll
    for (int mi = 0; mi < 4; ++mi)
#pragma unroll
      for (int ni = 0; ni < 4; ++ni)
        acc[mi][ni] =
            __builtin_amdgcn_mfma_f32_16x16x32_bf16(a[mi], b[ni], acc[mi][ni], 0, 0, 0);
    __syncthreads();
    cur ^= 1;
  }

#pragma unroll
  for (int mi = 0; mi < 4; ++mi) {
    int row = m0 + wm * 64 + mi * 16 + ((lane >> 4) << 2);
#pragma unroll
    for (int ni = 0; ni < 4; ++ni) {
      int col = n0 + wn * 64 + ni * 16 + (lane & 15);
#pragma unroll
      for (int r = 0; r < 4; ++r) {
        float v = acc[mi][ni][r];
        if (OUTF32)
          ((float*)Cout)[(size_t)(row + r) * N + col] = v + bias[col];
        else
          ((uint16_t*)Cout)[(size_t)(row + r) * N + col] = f2b(v);
      }
    }
  }
}

// ---------------- flash attention (causal), pipelined 32x32 S^T / O^T ----------
// 1024 blocks: bh = d&63, qb via Latin square (CU-coset balance). 4 waves x 32 q.
// KV tile 64. K double-buffered LDS, V TRIPLE-buffered LDS (PV of tile t-1 runs in
// iteration t -> its V buffer must survive one extra iteration).
// Steady state has ZERO cross-lane shuffles: defer-max skips the pair-max; l kept as
// per-lane partial, merged once at the end.
__global__ __launch_bounds__(256, 3) void flash_attn(const uint16_t* __restrict__ qkv,
                                                     uint16_t* __restrict__ attnb) {
  const int T = 2048, D3 = 3072;
  const float CSC = 0.125f * 1.44269504f;  // scale * log2(e)
  __shared__ alignas(16) uint16_t Ks[2][64 * 64];
  __shared__ alignas(16) uint16_t Vt[3][64 * 64];   // V^T: [hd][kv]

  int d = blockIdx.x;
  int bh = d & 63;
  int e = d >> 6;
  int hh = e >> 2, aa = e & 3;
  int qb = 4 * hh + ((aa + hh) & 3);   // Latin square
  int b = bh >> 4, h = bh & 15;
  int q0 = qb * 128;

  int tid = threadIdx.x, lane = tid & 63, wid = tid >> 6;
  int l31 = lane & 31, hi = lane >> 5;
  int qw = q0 + wid * 32;
  int swz = (lane & 7) << 3;

  size_t base = (size_t)b * T * D3;
  int hoff = h * 64;
  const uint16_t* kbase = &qkv[base + 1024 + hoff];
  const uint16_t* vbase = &qkv[base + 2048 + hoff];

  // Q frags (B-operand): col=q=l31, k = hd = 16*h4 + 8*hi + j
  bfx8 qf[4];
  {
    const uint16_t* qp = &qkv[base + (size_t)(qw + l31) * D3 + hoff + 8 * hi];
#pragma unroll
    for (int h4 = 0; h4 < 4; ++h4) qf[h4] = *(const bfx8*)(qp + 16 * h4);
  }

  float mC = -1e30f, l_r = 0.f;    // l_r: PER-LANE partial (merged at end)
  f32x16 acc0 = {}, acc1 = {};
  bfx8 pf[4];                       // packed P frags of previous tile
  int smax_prev = -1;               // <0: no pending PV
  int vb_prev = 0;

  int ntile = 2 * qb + 2;

  int krow = wid * 16 + (lane >> 3);
  int kc = ((lane & 7) << 3) ^ ((krow & 7) << 3);
  int vr = (tid & 31) * 2;
  int vc = (tid >> 5) * 8;
  uint4 vreg0, vreg1;

  auto loadV = [&](int kv0) {
    vreg0 = *(const uint4*)&vbase[(size_t)(kv0 + vr) * D3 + vc];
    vreg1 = *(const uint4*)&vbase[(size_t)(kv0 + vr + 1) * D3 + vc];
  };
  auto stageK = [&](int buf, int kv0) {
    gld16(&kbase[(size_t)(kv0 + krow) * D3 + kc], &Ks[buf][wid * 1024]);
    gld16(&kbase[(size_t)(kv0 + krow + 8) * D3 + kc], &Ks[buf][wid * 1024 + 512]);
  };
  auto writeV = [&](int vb) {
    union { uint4 v; uint16_t u[8]; } a, c;
    a.v = vreg0; c.v = vreg1;
#pragma unroll
    for (int j = 0; j < 8; ++j) {
      int hd = vc + j;
      uint32_t pk = (uint32_t)a.u[j] | ((uint32_t)c.u[j] << 16);
      *(uint32_t*)&Vt[vb][hd * 64 + (vr ^ ((hd & 7) << 3))] = pk;
    }
  };
  auto doPV = [&](int vb, int smx) {
    const uint16_t* vp = &Vt[vb][0];
    __builtin_amdgcn_s_setprio(1);
#pragma unroll
    for (int s = 0; s < 4; ++s) {
      if (s <= smx) {
        bfx8 v0 = *(const bfx8*)&vp[l31 * 64 + ((16 * s + 8 * hi) ^ swz)];
        acc0 = __builtin_amdgcn_mfma_f32_32x32x16_bf16(v0, pf[s], acc0, 0, 0, 0);
        bfx8 v1 = *(const bfx8*)&vp[(32 + l31) * 64 + ((16 * s + 8 * hi) ^ swz)];
        acc1 = __builtin_amdgcn_mfma_f32_32x32x16_bf16(v1, pf[s], acc1, 0, 0, 0);
      }
    }
    __builtin_amdgcn_s_setprio(0);
  };

  loadV(0);
  stageK(0, 0);
  writeV(0);
  __syncthreads();

  for (int kt = 0; kt < ntile; ++kt) {
    int kv0 = kt << 6;
    bool pre = (kt + 1 < ntile);
    if (pre) { loadV((kt + 1) << 6); stageK((kt + 1) & 1, (kt + 1) << 6); }

    int curK = kt & 1;
    bool active = (kv0 <= qw);
    int tmax = (qw > kv0) ? 2 : 1;   // sub-tile 1 fully masked when qw==kv0
    f32x16 st0 = {}, st1 = {};

    if (active) {
      // ---- S^T = K * Q^T ----
      __builtin_amdgcn_s_setprio(1);
#pragma unroll
      for (int h4 = 0; h4 < 4; ++h4) {
        bfx8 kf0 = *(const bfx8*)&Ks[curK][l31 * 64 + ((16 * h4 + 8 * hi) ^ swz)];
        st0 = __builtin_amdgcn_mfma_f32_32x32x16_bf16(kf0, qf[h4], st0, 0, 0, 0);
        if (tmax == 2) {
          bfx8 kf1 = *(const bfx8*)&Ks[curK][(32 + l31) * 64 + ((16 * h4 + 8 * hi) ^ swz)];
          st1 = __builtin_amdgcn_mfma_f32_32x32x16_bf16(kf1, qf[h4], st1, 0, 0, 0);
        }
      }
      __builtin_amdgcn_s_setprio(0);
    }

    // ---- PV of PREVIOUS tile (overlaps with softmax below; before any rescale) ----
    if (smax_prev >= 0) {
      doPV(vb_prev, smax_prev);
      smax_prev = -1;
    }

    if (active) {
      // ---- softmax (lane-local rows; st becomes P in place) ----
      int q = qw + l31;
      float mx0 = -1e30f, mx1 = -1e30f;
      if (kv0 == qw) {   // diagonal sub-tile 0 needs masking
#pragma unroll
        for (int r = 0; r < 16; ++r) {
          int kv = kv0 + (r & 3) + 8 * (r >> 2) + 4 * hi;
          float v = st0[r];
          if (kv > q) v = -1e30f;
          st0[r] = v;
          mx0 = fmaxf(mx0, v);
        }
      } else {
#pragma unroll
        for (int r = 0; r < 16; ++r) mx0 = fmaxf(mx0, st0[r]);
      }
      if (tmax == 2) {
        if (kv0 + 32 == qw) {   // diagonal sub-tile 1 needs masking
#pragma unroll
          for (int r = 0; r < 16; ++r) {
            int kv = kv0 + 32 + (r & 3) + 8 * (r >> 2) + 4 * hi;
            float v = st1[r];
            if (kv > q) v = -1e30f;
            st1[r] = v;
            mx1 = fmaxf(mx1, v);
          }
        } else {
#pragma unroll
          for (int r = 0; r < 16; ++r) mx1 = fmaxf(mx1, st1[r]);
        }
      }
      float mS = fmaxf(mx0, mx1) * CSC;
      if (!__all(mS - mC <= 8.0f)) {   // defer-max: rare path has the only shuffles
        float mSp = fmaxf(mS, __shfl_xor(mS, 32));
        float mCn = fmaxf(mC, mSp);
        float fac = __builtin_amdgcn_exp2f(mC - mCn);
        mC = mCn;
        l_r *= fac;
        acc0 *= fac;   // ordered after doPV (register deps)
        acc1 *= fac;
      }
      float l0 = 0.f, l1 = 0.f, l2 = 0.f, l3 = 0.f;
#pragma unroll
      for (int r = 0; r < 16; r += 4) {
        float e0 = __builtin_amdgcn_exp2f(fmaf(st0[r], CSC, -mC));
        float e1 = __builtin_amdgcn_exp2f(fmaf(st0[r + 1], CSC, -mC));
        float e2 = __builtin_amdgcn_exp2f(fmaf(st0[r + 2], CSC, -mC));
        float e3 = __builtin_amdgcn_exp2f(fmaf(st0[r + 3], CSC, -mC));
        st0[r] = e0; st0[r + 1] = e1; st0[r + 2] = e2; st0[r + 3] = e3;
        l0 += e0; l1 += e1; l2 += e2; l3 += e3;
      }
      if (tmax == 2) {
#pragma unroll
        for (int r = 0; r < 16; r += 4) {
          float e0 = __builtin_amdgcn_exp2f(fmaf(st1[r], CSC, -mC));
          float e1 = __builtin_amdgcn_exp2f(fmaf(st1[r + 1], CSC, -mC));
          float e2 = __builtin_amdgcn_exp2f(fmaf(st1[r + 2], CSC, -mC));
          float e3 = __builtin_amdgcn_exp2f(fmaf(st1[r + 3], CSC, -mC));
          st1[r] = e0; st1[r + 1] = e1; st1[r + 2] = e2; st1[r + 3] = e3;
          l0 += e0; l1 += e1; l2 += e2; l3 += e3;
        }
      }
      l_r += (l0 + l1) + (l2 + l3);

      // ---- pack P -> bf16 B-frags in registers (cvt_pk + permlane32_swap) ----
      int smax = (qw + 31 - kv0) >> 4;
      if (smax > 3) smax = 3;
#pragma unroll
      for (int s = 0; s < 4; ++s) {
        if (s <= smax) {
          int pb = 8 * (s & 1);
          uint32_t W0, W1, W2, W3;
          if (s < 2) {
            W0 = cvt_pk(st0[pb + 0], st0[pb + 1]);
            W1 = cvt_pk(st0[pb + 2], st0[pb + 3]);
            W2 = cvt_pk(st0[pb + 4], st0[pb + 5]);
            W3 = cvt_pk(st0[pb + 6], st0[pb + 7]);
          } else {
            W0 = cvt_pk(st1[pb + 0], st1[pb + 1]);
            W1 = cvt_pk(st1[pb + 2], st1[pb + 3]);
            W2 = cvt_pk(st1[pb + 4], st1[pb + 5]);
            W3 = cvt_pk(st1[pb + 6], st1[pb + 7]);
          }
          auto rA = __builtin_amdgcn_permlane32_swap(W0, W2, false, false);
          auto rB = __builtin_amdgcn_permlane32_swap(W1, W3, false, false);
          union { uint32_t u[4]; bfx8 v; } pk;
          pk.u[0] = rA[0]; pk.u[1] = rB[0]; pk.u[2] = rA[1]; pk.u[3] = rB[1];
          pf[s] = pk.v;
        }
      }
      smax_prev = smax;
      vb_prev = kt % 3;
    }

    if (pre) writeV((kt + 1) % 3);
    __syncthreads();
  }

  // ---- drain pending PV ----
  if (smax_prev >= 0) doPV(vb_prev, smax_prev);

  // ---- epilogue: merge l across lane pair, normalize, transpose, store ----
  float l_tot = l_r + __shfl_xor(l_r, 32);
  __syncthreads();
  uint16_t* ow = ((uint16_t*)Ks) + wid * 2048;  // per-warp [32 q][64 hd]
  float rl = 1.0f / l_tot;
#pragma unroll
  for (int f = 0; f < 2; ++f) {
#pragma unroll
    for (int r = 0; r < 16; r += 2) {
      int hd = 32 * f + (r & 3) + 8 * (r >> 2) + 4 * hi;
      float v0 = (f ? acc1[r] : acc0[r]) * rl;
      float v1 = (f ? acc1[r + 1] : acc0[r + 1]) * rl;
      *(uint32_t*)&ow[l31 * 64 + (hd ^ ((l31 & 7) << 3))] = cvt_pk(v0, v1);
    }
  }
  __syncthreads();
  int row = lane >> 1, cb = (lane & 1) * 32;
  int q = q0 + wid * 32 + row;
  int rs = (row & 7) << 3;
  uint16_t* dst = &attnb[(size_t)(b * T + q) * 1024 + hoff + cb];
#pragma unroll
  for (int cc = 0; cc < 4; ++cc)
    *(uint4*)&dst[cc * 8] = *(const uint4*)&ow[row * 64 + ((cb + cc * 8) ^ rs)];
}

// ---------------- host ----------------
extern "C" void kernel_launch(void* const* d_in, const int* in_sizes, int n_in,
                              void* d_out, int out_size, void* d_ws, size_t ws_size,
                              hipStream_t stream) {
  const float* x = (const float*)d_in[0];
  const float* qkv_w = (const float*)d_in[1];
  const float* out_w = (const float*)d_in[2];
  const float* out_b = (const float*)d_in[3];
  float* out = (float*)d_out;

  char* ws = (char*)d_ws;
  uint16_t* xb    = (uint16_t*)(ws);
  uint16_t* qkvb  = (uint16_t*)(ws + 16777216);
  uint16_t* attnb = (uint16_t*)(ws + 67108864);
  uint16_t* wqkvb = (uint16_t*)(ws + 83886080);
  uint16_t* wob   = (uint16_t*)(ws + 90177536);

  cvt_bf16<<<4096, 256, 0, stream>>>(x, xb, 1048576);
  cvt_bf16<<<1536, 256, 0, stream>>>(qkv_w, wqkvb, 393216);
  cvt_bf16<<<512, 256, 0, stream>>>(out_w, wob, 131072);

  gemm_bt<0><<<1536, 256, 0, stream>>>(xb, wqkvb, (void*)qkvb, nullptr,
                                       8192, 3072, 1024, 24, 1536);
  flash_attn<<<1024, 256, 0, stream>>>(qkvb, attnb);
  gemm_bt<1><<<512, 256, 0, stream>>>(attnb, wob, (void*)out, out_b,
                                      8192, 1024, 1024, 8, 512);
}

// Round 5
// 193.869 us; speedup vs baseline: 1.8103x; 1.0178x over previous
//
#include <hip/hip_runtime.h>
#include <stdint.h>

// Shapes (fixed): x [4,2048,1024] f32, qkv_w [3072,1024] f32, out_w [1024,1024] f32,
// out_b [1024] f32, out [4,2048,1024] f32.
// Pipeline: cvt->bf16, GEMM qkv = x@qkv_w^T, flash attn (32x32 S^T/O^T, in-reg softmax,
// cross-tile PV pipeline, counted-vmcnt raw barriers, uniform qb-paired blocks),
// GEMM out = attn@out_w^T + b.

typedef __bf16 bfx8 __attribute__((ext_vector_type(8)));
typedef float f32x4 __attribute__((ext_vector_type(4)));
typedef float f32x16 __attribute__((ext_vector_type(16)));

__device__ __forceinline__ uint16_t f2b(float f) {
  uint32_t u = __float_as_uint(f);
  u += 0x7fff + ((u >> 16) & 1);   // RNE
  return (uint16_t)(u >> 16);
}

__device__ __forceinline__ uint32_t cvt_pk(float lo, float hi) {
  uint32_t r;
  asm("v_cvt_pk_bf16_f32 %0, %1, %2" : "=v"(r) : "v"(lo), "v"(hi));
  return r;
}

__device__ __forceinline__ void gld16(const void* g, void* l) {
  __builtin_amdgcn_global_load_lds((const __attribute__((address_space(1))) void*)g,
                                   (__attribute__((address_space(3))) void*)l,
                                   16, 0, 0);
}

// ---------------- f32 -> bf16 convert (8 elems/thread) ----------------
__global__ __launch_bounds__(256) void cvt_bf16(const float* __restrict__ in,
                                                uint16_t* __restrict__ out, int n8) {
  int i = blockIdx.x * 256 + threadIdx.x;
  if (i >= n8) return;
  float4 a = ((const float4*)in)[2 * i];
  float4 b = ((const float4*)in)[2 * i + 1];
  union { uint16_t u[8]; uint4 v; } pk;
  pk.u[0] = f2b(a.x); pk.u[1] = f2b(a.y); pk.u[2] = f2b(a.z); pk.u[3] = f2b(a.w);
  pk.u[4] = f2b(b.x); pk.u[5] = f2b(b.y); pk.u[6] = f2b(b.z); pk.u[7] = f2b(b.w);
  ((uint4*)out)[i] = pk.v;
}

// ---------------- GEMM: C[M,N] = A[M,K] * B[N,K]^T (+bias) ----------------
template <int OUTF32>
__global__ __launch_bounds__(256) void gemm_bt(const uint16_t* __restrict__ A,
                                               const uint16_t* __restrict__ B,
                                               void* __restrict__ Cout,
                                               const float* __restrict__ bias,
                                               int M, int N, int K, int nbx, int nwg) {
  __shared__ alignas(16) uint16_t As[2][128 * 32];
  __shared__ alignas(16) uint16_t Bs[2][128 * 32];

  int did = blockIdx.x;
  int wg = (did & 7) * (nwg >> 3) + (did >> 3);
  int bx = wg % nbx, by = wg / nbx;
  int m0 = by * 128, n0 = bx * 128;

  int tid = threadIdx.x;
  int lane = tid & 63, wid = tid >> 6;
  int wm = wid >> 1, wn = wid & 1;

  int rs = wid * 16 + (lane >> 2);
  int cs = (lane & 3) * 8;

  f32x4 acc[4][4] = {};

  auto stage = [&](int buf, int kt) {
    int k0 = kt * 32;
    gld16(&A[(size_t)(m0 + rs) * K + k0 + cs],      &As[buf][wid * 512]);
    gld16(&A[(size_t)(m0 + rs + 64) * K + k0 + cs], &As[buf][wid * 512 + 2048]);
    gld16(&B[(size_t)(n0 + rs) * K + k0 + cs],      &Bs[buf][wid * 512]);
    gld16(&B[(size_t)(n0 + rs + 64) * K + k0 + cs], &Bs[buf][wid * 512 + 2048]);
  };

  stage(0, 0);
  __syncthreads();

  int nk = K >> 5;
  int cur = 0;
  int ko = (lane >> 4) * 8;
  for (int kt = 0; kt < nk; ++kt) {
    if (kt + 1 < nk) stage(cur ^ 1, kt + 1);
    bfx8 a[4], b[4];
#pragma unroll
    for (int mi = 0; mi < 4; ++mi)
      a[mi] = *(const bfx8*)&As[cur][(wm * 64 + mi * 16 + (lane & 15)) * 32 + ko];
#pragma unroll
    for (int ni = 0; ni < 4; ++ni)
      b[ni] = *(const bfx8*)&Bs[cur][(wn * 64 + ni * 16 + (lane & 15)) * 32 + ko];
#pragma unroll
    for (int mi = 0; mi < 4; ++mi)
#pragma unroll
      for (int ni = 0; ni < 4; ++ni)
        acc[mi][ni] =
            __builtin_amdgcn_mfma_f32_16x16x32_bf16(a[mi], b[ni], acc[mi][ni], 0, 0, 0);
    __syncthreads();
    cur ^= 1;
  }

#pragma unroll
  for (int mi = 0; mi < 4; ++mi) {
    int row = m0 + wm * 64 + mi * 16 + ((lane >> 4) << 2);
#pragma unroll
    for (int ni = 0; ni < 4; ++ni) {
      int col = n0 + wn * 64 + ni * 16 + (lane & 15);
#pragma unroll
      for (int r = 0; r < 4; ++r) {
        float v = acc[mi][ni][r];
        if (OUTF32)
          ((float*)Cout)[(size_t)(row + r) * N + col] = v + bias[col];
        else
          ((uint16_t*)Cout)[(size_t)(row + r) * N + col] = f2b(v);
      }
    }
  }
}

// ---------------- flash attention (causal), pipelined 32x32 S^T / O^T ----------
// 512 UNIFORM blocks: bh = d&63, a = d>>6 (0..7); block processes qb = 15-a then
// qb = a sequentially -> every block does exactly 34 kv-tiles. 4 waves x 32 q.
// Distance-2 prefetch: at iter t issue K/V global loads for tile t+2; K triple-buffered
// LDS (global_load_lds), V triple-buffered LDS via 2-bank register staging (2x unrolled
// loop keeps bank indices compile-time). Raw s_barrier with COUNTED vmcnt(4): this
// iteration's 4 loads stay in flight across the barrier (no per-tile HBM drain).
// Buffer rotation mod 3: write K(t+2), read K(t), read V(t-1), write V(t+1) - disjoint.
__global__ __launch_bounds__(256, 2) void flash_attn(const uint16_t* __restrict__ qkv,
                                                     uint16_t* __restrict__ attnb) {
  const int T = 2048, D3 = 3072;
  const float CSC = 0.125f * 1.44269504f;  // scale * log2(e)
  __shared__ alignas(16) uint16_t Ks[3][64 * 64];
  __shared__ alignas(16) uint16_t Vt[3][64 * 64];   // V^T: [hd][kv]

  int d = blockIdx.x;
  int bh = d & 63;
  int a = d >> 6;              // 0..7
  int b = bh >> 4, h = bh & 15;

  int tid = threadIdx.x, lane = tid & 63, wid = tid >> 6;
  int l31 = lane & 31, hi = lane >> 5;
  int swz = (lane & 7) << 3;

  size_t base = (size_t)b * T * D3;
  int hoff = h * 64;
  const uint16_t* kbase = &qkv[base + 1024 + hoff];
  const uint16_t* vbase = &qkv[base + 2048 + hoff];

  int krow = wid * 16 + (lane >> 3);
  int kc = ((lane & 7) << 3) ^ ((krow & 7) << 3);
  int vr = (tid & 31) * 2;
  int vc = (tid >> 5) * 8;

  for (int p = 0; p < 2; ++p) {
    int qb = (p == 0) ? (15 - a) : a;   // long part first
    int q0 = qb << 7;
    int qw = q0 + wid * 32;
    int ntile = 2 * qb + 2;             // even

    float mC = -1e30f, l_r = 0.f;       // l_r: per-lane partial
    f32x16 acc0 = {}, acc1 = {};
    bfx8 pf[4];
    int smax_prev = -1, vb_prev = 0;

    // Q frags (B-operand): col=q=l31, k = hd = 16*h4 + 8*hi + j
    bfx8 qf[4];
    {
      const uint16_t* qp = &qkv[base + (size_t)(qw + l31) * D3 + hoff + 8 * hi];
#pragma unroll
      for (int h4 = 0; h4 < 4; ++h4) qf[h4] = *(const bfx8*)(qp + 16 * h4);
    }

    uint4 vA0, vA1, vB0, vB1;   // two V register banks (tile parity)

    auto loadV = [&](int kv0, uint4& r0, uint4& r1) {
      r0 = *(const uint4*)&vbase[(size_t)(kv0 + vr) * D3 + vc];
      r1 = *(const uint4*)&vbase[(size_t)(kv0 + vr + 1) * D3 + vc];
    };
    auto stageK = [&](int buf, int kv0) {
      gld16(&kbase[(size_t)(kv0 + krow) * D3 + kc], &Ks[buf][wid * 1024]);
      gld16(&kbase[(size_t)(kv0 + krow + 8) * D3 + kc], &Ks[buf][wid * 1024 + 512]);
    };
    auto writeV = [&](int vb, const uint4& r0, const uint4& r1) {
      union { uint4 v; uint16_t u[8]; } x, y;
      x.v = r0; y.v = r1;
#pragma unroll
      for (int j = 0; j < 8; ++j) {
        int hd = vc + j;
        uint32_t pk = (uint32_t)x.u[j] | ((uint32_t)y.u[j] << 16);
        *(uint32_t*)&Vt[vb][hd * 64 + (vr ^ ((hd & 7) << 3))] = pk;
      }
    };
    auto doPV = [&]() {
      const uint16_t* vp = &Vt[vb_prev][0];
      __builtin_amdgcn_s_setprio(1);
#pragma unroll
      for (int s = 0; s < 4; ++s) {
        if (s <= smax_prev) {
          bfx8 v0 = *(const bfx8*)&vp[l31 * 64 + ((16 * s + 8 * hi) ^ swz)];
          acc0 = __builtin_amdgcn_mfma_f32_32x32x16_bf16(v0, pf[s], acc0, 0, 0, 0);
          bfx8 v1 = *(const bfx8*)&vp[(32 + l31) * 64 + ((16 * s + 8 * hi) ^ swz)];
          acc1 = __builtin_amdgcn_mfma_f32_32x32x16_bf16(v1, pf[s], acc1, 0, 0, 0);
        }
      }
      __builtin_amdgcn_s_setprio(0);
    };

    // ---- prologue: stage tiles 0,1 fully; full drain once ----
    loadV(0, vA0, vA1);
    stageK(0, 0);
    writeV(0, vA0, vA1);          // compiler inserts the vmcnt wait for vA regs
    loadV(64, vB0, vB1);          // tile 1 -> bank B (written at iter 0)
    stageK(1, 64);
    asm volatile("s_waitcnt vmcnt(0) lgkmcnt(0)" ::: "memory");
    __builtin_amdgcn_s_barrier();
    __builtin_amdgcn_sched_barrier(0);

    auto subiter = [&](int t, uint4& f0, uint4& f1, uint4& c0, uint4& c1) {
      int kv0 = t << 6;
      bool issue = (t + 2 < ntile);
      if (issue) {
        loadV((t + 2) << 6, f0, f1);
        stageK((t + 2) % 3, (t + 2) << 6);
      }
      bool active = (kv0 <= qw);
      int tmax = (qw > kv0) ? 2 : 1;
      f32x16 st0 = {}, st1 = {};
      if (active) {
        // ---- S^T = K * Q^T ----
        const uint16_t* kp = &Ks[t % 3][0];
        __builtin_amdgcn_s_setprio(1);
#pragma unroll
        for (int h4 = 0; h4 < 4; ++h4) {
          bfx8 kf0 = *(const bfx8*)&kp[l31 * 64 + ((16 * h4 + 8 * hi) ^ swz)];
          st0 = __builtin_amdgcn_mfma_f32_32x32x16_bf16(kf0, qf[h4], st0, 0, 0, 0);
          if (tmax == 2) {
            bfx8 kf1 = *(const bfx8*)&kp[(32 + l31) * 64 + ((16 * h4 + 8 * hi) ^ swz)];
            st1 = __builtin_amdgcn_mfma_f32_32x32x16_bf16(kf1, qf[h4], st1, 0, 0, 0);
          }
        }
        __builtin_amdgcn_s_setprio(0);
      }

      // ---- PV of PREVIOUS tile (before any rescale of acc) ----
      if (smax_prev >= 0) { doPV(); smax_prev = -1; }

      if (active) {
        // ---- softmax (lane-local rows; st becomes P in place) ----
        int q = qw + l31;
        float mx0 = -1e30f, mx1 = -1e30f;
        if (kv0 == qw) {
#pragma unroll
          for (int r = 0; r < 16; ++r) {
            int kv = kv0 + (r & 3) + 8 * (r >> 2) + 4 * hi;
            float v = st0[r];
            if (kv > q) v = -1e30f;
            st0[r] = v;
            mx0 = fmaxf(mx0, v);
          }
        } else {
#pragma unroll
          for (int r = 0; r < 16; ++r) mx0 = fmaxf(mx0, st0[r]);
        }
        if (tmax == 2) {
          if (kv0 + 32 == qw) {
#pragma unroll
            for (int r = 0; r < 16; ++r) {
              int kv = kv0 + 32 + (r & 3) + 8 * (r >> 2) + 4 * hi;
              float v = st1[r];
              if (kv > q) v = -1e30f;
              st1[r] = v;
              mx1 = fmaxf(mx1, v);
            }
          } else {
#pragma unroll
            for (int r = 0; r < 16; ++r) mx1 = fmaxf(mx1, st1[r]);
          }
        }
        float mS = fmaxf(mx0, mx1) * CSC;
        if (!__all(mS - mC <= 8.0f)) {   // defer-max: rare path has the only shuffle
          float mSp = fmaxf(mS, __shfl_xor(mS, 32));
          float mCn = fmaxf(mC, mSp);
          float fac = __builtin_amdgcn_exp2f(mC - mCn);
          mC = mCn;
          l_r *= fac;
          acc0 *= fac;
          acc1 *= fac;
        }
        float l0 = 0.f, l1 = 0.f, l2 = 0.f, l3 = 0.f;
#pragma unroll
        for (int r = 0; r < 16; r += 4) {
          float e0 = __builtin_amdgcn_exp2f(fmaf(st0[r], CSC, -mC));
          float e1 = __builtin_amdgcn_exp2f(fmaf(st0[r + 1], CSC, -mC));
          float e2 = __builtin_amdgcn_exp2f(fmaf(st0[r + 2], CSC, -mC));
          float e3 = __builtin_amdgcn_exp2f(fmaf(st0[r + 3], CSC, -mC));
          st0[r] = e0; st0[r + 1] = e1; st0[r + 2] = e2; st0[r + 3] = e3;
          l0 += e0; l1 += e1; l2 += e2; l3 += e3;
        }
        if (tmax == 2) {
#pragma unroll
          for (int r = 0; r < 16; r += 4) {
            float e0 = __builtin_amdgcn_exp2f(fmaf(st1[r], CSC, -mC));
            float e1 = __builtin_amdgcn_exp2f(fmaf(st1[r + 1], CSC, -mC));
            float e2 = __builtin_amdgcn_exp2f(fmaf(st1[r + 2], CSC, -mC));
            float e3 = __builtin_amdgcn_exp2f(fmaf(st1[r + 3], CSC, -mC));
            st1[r] = e0; st1[r + 1] = e1; st1[r + 2] = e2; st1[r + 3] = e3;
            l0 += e0; l1 += e1; l2 += e2; l3 += e3;
          }
        }
        l_r += (l0 + l1) + (l2 + l3);

        // ---- pack P -> bf16 B-frags in registers ----
        int smax = (qw + 31 - kv0) >> 4;
        if (smax > 3) smax = 3;
#pragma unroll
        for (int s = 0; s < 4; ++s) {
          if (s <= smax) {
            int pb = 8 * (s & 1);
            uint32_t W0, W1, W2, W3;
            if (s < 2) {
              W0 = cvt_pk(st0[pb + 0], st0[pb + 1]);
              W1 = cvt_pk(st0[pb + 2], st0[pb + 3]);
              W2 = cvt_pk(st0[pb + 4], st0[pb + 5]);
              W3 = cvt_pk(st0[pb + 6], st0[pb + 7]);
            } else {
              W0 = cvt_pk(st1[pb + 0], st1[pb + 1]);
              W1 = cvt_pk(st1[pb + 2], st1[pb + 3]);
              W2 = cvt_pk(st1[pb + 4], st1[pb + 5]);
              W3 = cvt_pk(st1[pb + 6], st1[pb + 7]);
            }
            auto rA = __builtin_amdgcn_permlane32_swap(W0, W2, false, false);
            auto rB = __builtin_amdgcn_permlane32_swap(W1, W3, false, false);
            union { uint32_t u[4]; bfx8 v; } pk;
            pk.u[0] = rA[0]; pk.u[1] = rB[0]; pk.u[2] = rA[1]; pk.u[3] = rB[1];
            pf[s] = pk.v;
          }
        }
        smax_prev = smax;
        vb_prev = t % 3;
      }

      if (t + 1 < ntile) writeV((t + 1) % 3, c0, c1);

      if (issue)
        asm volatile("s_waitcnt vmcnt(4) lgkmcnt(0)" ::: "memory");  // keep this iter's 4 in flight
      else
        asm volatile("s_waitcnt vmcnt(0) lgkmcnt(0)" ::: "memory");  // tail: full drain
      __builtin_amdgcn_s_barrier();
      __builtin_amdgcn_sched_barrier(0);
    };

    for (int t = 0; t < ntile; t += 2) {
      subiter(t, vA0, vA1, vB0, vB1);       // fill A (tile t+2), consume B (tile t+1)
      subiter(t + 1, vB0, vB1, vA0, vA1);   // fill B (tile t+3), consume A (tile t+2)
    }
    if (smax_prev >= 0) doPV();

    // ---- epilogue: merge l across lane pair, normalize, transpose, store ----
    float l_tot = l_r + __shfl_xor(l_r, 32);
    __syncthreads();   // all waves done reading K/V LDS before overlay
    uint16_t* ow = ((uint16_t*)Ks) + wid * 2048;  // per-warp [32 q][64 hd] (warp-private)
    float rl = 1.0f / l_tot;
#pragma unroll
    for (int f = 0; f < 2; ++f) {
#pragma unroll
      for (int r = 0; r < 16; r += 2) {
        int hd = 32 * f + (r & 3) + 8 * (r >> 2) + 4 * hi;
        float v0 = (f ? acc1[r] : acc0[r]) * rl;
        float v1 = (f ? acc1[r + 1] : acc0[r + 1]) * rl;
        *(uint32_t*)&ow[l31 * 64 + (hd ^ ((l31 & 7) << 3))] = cvt_pk(v0, v1);
      }
    }
    // warp-private region: no barrier needed between write and read
    int row = lane >> 1, cb = (lane & 1) * 32;
    int q = q0 + wid * 32 + row;
    int rs = (row & 7) << 3;
    uint16_t* dst = &attnb[(size_t)(b * T + q) * 1024 + hoff + cb];
#pragma unroll
    for (int cc = 0; cc < 4; ++cc)
      *(uint4*)&dst[cc * 8] = *(const uint4*)&ow[row * 64 + ((cb + cc * 8) ^ rs)];
    __syncthreads();   // epilogue reads done before next part restages Ks
  }
}

// ---------------- host ----------------
extern "C" void kernel_launch(void* const* d_in, const int* in_sizes, int n_in,
                              void* d_out, int out_size, void* d_ws, size_t ws_size,
                              hipStream_t stream) {
  const float* x = (const float*)d_in[0];
  const float* qkv_w = (const float*)d_in[1];
  const float* out_w = (const float*)d_in[2];
  const float* out_b = (const float*)d_in[3];
  float* out = (float*)d_out;

  char* ws = (char*)d_ws;
  uint16_t* xb    = (uint16_t*)(ws);
  uint16_t* qkvb  = (uint16_t*)(ws + 16777216);
  uint16_t* attnb = (uint16_t*)(ws + 67108864);
  uint16_t* wqkvb = (uint16_t*)(ws + 83886080);
  uint16_t* wob   = (uint16_t*)(ws + 90177536);

  cvt_bf16<<<4096, 256, 0, stream>>>(x, xb, 1048576);
  cvt_bf16<<<1536, 256, 0, stream>>>(qkv_w, wqkvb, 393216);
  cvt_bf16<<<512, 256, 0, stream>>>(out_w, wob, 131072);

  gemm_bt<0><<<1536, 256, 0, stream>>>(xb, wqkvb, (void*)qkvb, nullptr,
                                       8192, 3072, 1024, 24, 1536);
  flash_attn<<<512, 256, 0, stream>>>(qkvb, attnb);
  gemm_bt<1><<<512, 256, 0, stream>>>(attnb, wob, (void*)out, out_b,
                                      8192, 1024, 1024, 8, 512);
}